// Round 9
// baseline (308.700 us; speedup 1.0000x reference)
//
#include <hip/hip_runtime.h>

#define H 2048
#define NH 16
#define NKV 4
#define HD 128
#define CTX 8192
#define IDIM 8192
#define EPS 1e-6f
#define SCALE 0.08838834764831845f

__device__ __forceinline__ float wave_sum(float x){
#pragma unroll
    for(int o=32;o>0;o>>=1) x += __shfl_xor(x,o,64);
    return x;
}
__device__ __forceinline__ float wave_max(float x){
#pragma unroll
    for(int o=32;o>0;o>>=1) x = fmaxf(x,__shfl_xor(x,o,64));
    return x;
}
__device__ __forceinline__ void keep4(const float4& v){
    asm volatile("" :: "v"(v.x), "v"(v.y), "v"(v.z), "v"(v.w));
}
// Async global->LDS stage: 16B/lane, fire-and-forget (no dest VGPRs). Dest =
// uniform base + lane*16.
__device__ __forceinline__ void stage16(const float* g, float* l){
    __builtin_amdgcn_global_load_lds(
        (const __attribute__((address_space(1))) void*)g,
        (__attribute__((address_space(3))) void*)l, 16, 0, 0);
}
// Counted vmem wait (T4): never drain to 0 in a consume loop.
#define WV(N) asm volatile("s_waitcnt vmcnt(" #N ")" ::: "memory")

// ---------- K1: ln1-RMSNorm + QKV matvec. grid 576 x 512 ---------- (unchanged)
__global__ __launch_bounds__(512) void k_qkv(const float* __restrict__ Wq,
                                             const float* __restrict__ Wk,
                                             const float* __restrict__ Wv,
                                             const float* __restrict__ hs,
                                             const float* __restrict__ ln1,
                                             float* __restrict__ qg,
                                             float* __restrict__ kvec,
                                             float* __restrict__ vvec){
    __shared__ __align__(16) float hw[H];          // 8KB
    __shared__ __align__(16) float wlds[8*2048];   // 64KB: one row per wave
    __shared__ float red[8];
    int tid = threadIdx.x, wid = tid>>6, lane = tid&63;
    int row = blockIdx.x*8 + wid;
    const float* wr; float* op;
    if(row < 4096)      { wr = Wq + (size_t)row*H;        op = qg   + row; }
    else if(row < 4608) { wr = Wk + (size_t)(row-4096)*H; op = kvec + (row-4096); }
    else                { wr = Wv + (size_t)(row-4608)*H; op = vvec + (row-4608); }
    float4 a  = *(const float4*)(hs  + tid*4);
    float4 wa = *(const float4*)(ln1 + tid*4);
#pragma unroll
    for(int i=0;i<8;i++) stage16(wr + i*256 + lane*4, wlds + wid*2048 + i*256);

    float ss = a.x*a.x + a.y*a.y + a.z*a.z + a.w*a.w;
    ss = wave_sum(ss);
    if(lane==0) red[wid] = ss;
    __syncthreads();
    float tot = red[0]+red[1]+red[2]+red[3]+red[4]+red[5]+red[6]+red[7];
    float rs = rsqrtf(tot/(float)H + EPS);
    *(float4*)(hw + tid*4) = make_float4(a.x*rs*wa.x, a.y*rs*wa.y, a.z*rs*wa.z, a.w*rs*wa.w);
    __syncthreads();

    float acc = 0.f;
#pragma unroll
    for(int i=0;i<8;i++){
        float4 rv = *(const float4*)(wlds + wid*2048 + i*256 + lane*4);
        float4 hv = *(const float4*)(hw + i*256 + lane*4);
        acc += rv.x*hv.x + rv.y*hv.y + rv.z*hv.z + rv.w*hv.w;
    }
    acc = wave_sum(acc);
    if(lane==0) *op = acc;
}

// ---------- K2: q/k RMS + RoPE + gate sigmoid. grid 20 x 64 ---------- (unchanged)
__global__ __launch_bounds__(64) void k_rope(const float* __restrict__ qg,
                                             const float* __restrict__ kvec,
                                             const float* __restrict__ vvec,
                                             const int* __restrict__ pos,
                                             const float* __restrict__ qn,
                                             const float* __restrict__ kn,
                                             const float* __restrict__ rc,
                                             const float* __restrict__ rsn,
                                             float* __restrict__ q_rope,
                                             float* __restrict__ gate_sig,
                                             float* __restrict__ knew,
                                             float* __restrict__ vnew){
    int b = blockIdx.x, lane = threadIdx.x;
    int p = pos[0];
    float c = rc[(size_t)p*64 + lane];
    float s = rsn[(size_t)p*64 + lane];
    if(b < NH){
        int h = b;
        float x1 = qg[h*256 + lane], x2 = qg[h*256 + 64 + lane];
        float ssq = wave_sum(x1*x1 + x2*x2);
        float r = rsqrtf(ssq/128.f + EPS);
        float n1 = x1*r*qn[lane];
        float n2 = x2*r*qn[lane+64];
        q_rope[h*128 + lane]      = n1*c - n2*s;
        q_rope[h*128 + 64 + lane] = n2*c + n1*s;
        float g1 = qg[h*256 + 128 + lane], g2 = qg[h*256 + 192 + lane];
        gate_sig[h*128 + lane]      = 1.f/(1.f + __expf(-g1));
        gate_sig[h*128 + 64 + lane] = 1.f/(1.f + __expf(-g2));
    } else {
        int j = b - NH;
        float x1 = kvec[j*128 + lane], x2 = kvec[j*128 + 64 + lane];
        float ssq = wave_sum(x1*x1 + x2*x2);
        float r = rsqrtf(ssq/128.f + EPS);
        float n1 = x1*r*kn[lane];
        float n2 = x2*r*kn[lane+64];
        knew[j*128 + lane]      = n1*c - n2*s;
        knew[j*128 + 64 + lane] = n2*c + n1*s;
        vnew[j*128 + lane]      = vvec[j*128 + lane];
        vnew[j*128 + 64 + lane] = vvec[j*128 + 64 + lane];
    }
}

// ---------- K3: flash-decode partials v2. grid (nchunk, NKV) x 256 ---------- (unchanged)
__global__ __launch_bounds__(256) void k_attn_part(const float* __restrict__ cache,
                                                   const float* __restrict__ q_rope,
                                                   const float* __restrict__ mask,
                                                   const int* __restrict__ pos,
                                                   const float* __restrict__ knew,
                                                   const float* __restrict__ vnew,
                                                   float* __restrict__ part_m,
                                                   float* __restrict__ part_l,
                                                   float* __restrict__ part_o,
                                                   int nchunk, int chunk){
    int j = blockIdx.y, ci = blockIdx.x, tid = threadIdx.x;
    int p = pos[0];
    __shared__ __align__(16) float q_s[512];
    __shared__ float s_s[512];
    __shared__ __align__(16) float V_s[128*128];
    __shared__ float m_s[4], l_s[4], sc_s[4];
    int lane = tid&63, w = tid>>6;
    int base0 = ci*chunk;

    q_s[tid]       = q_rope[j*512 + tid];
    q_s[256 + tid] = q_rope[j*512 + 256 + tid];
    if(tid < 4){ m_s[tid] = -3.0e38f; l_s[tid] = 0.f; }
    float o0=0.f,o1=0.f,o2=0.f,o3=0.f;
    __syncthreads();

    for(int s0=0; s0<chunk; s0+=128){
        if(w >= 2){
            const float* vb = cache + (size_t)NKV*CTX*HD + ((size_t)j*CTX + base0 + s0)*HD;
            int half = w - 2;
#pragma unroll
            for(int i=0;i<32;i++){
                int idx = half*32 + i;
                stage16(vb + idx*256 + lane*4, V_s + idx*256);
            }
        } else {
            int c = base0 + s0 + tid;
            const float* kr = (c==p) ? (knew + (size_t)j*HD)
                                     : (cache + ((size_t)j*CTX + c)*HD);
            float a0=0.f,a1=0.f,a2=0.f,a3=0.f;
            for(int d0=0; d0<HD; d0+=32){
                float4 u8[8];
#pragma unroll
                for(int t=0;t<8;t++) u8[t] = *(const float4*)(kr + d0 + t*4);
#pragma unroll
                for(int t=0;t<8;t++) keep4(u8[t]);
#pragma unroll
                for(int t=0;t<8;t++){
                    int dd = d0 + t*4;
                    const float* q0=q_s+dd; const float* q1=q_s+128+dd;
                    const float* q2=q_s+256+dd; const float* q3=q_s+384+dd;
                    a0 += q0[0]*u8[t].x+q0[1]*u8[t].y+q0[2]*u8[t].z+q0[3]*u8[t].w;
                    a1 += q1[0]*u8[t].x+q1[1]*u8[t].y+q1[2]*u8[t].z+q1[3]*u8[t].w;
                    a2 += q2[0]*u8[t].x+q2[1]*u8[t].y+q2[2]*u8[t].z+q2[3]*u8[t].w;
                    a3 += q3[0]*u8[t].x+q3[1]*u8[t].y+q3[2]*u8[t].z+q3[3]*u8[t].w;
                }
            }
            float mv = mask[c];
            s_s[tid]       = a0*SCALE + mv;
            s_s[128 + tid] = a1*SCALE + mv;
            s_s[256 + tid] = a2*SCALE + mv;
            s_s[384 + tid] = a3*SCALE + mv;
        }
        __syncthreads();

        int prow = p - (base0 + s0);
        if(prow >= 0 && prow < 128 && tid < 128)
            V_s[prow*128 + tid] = vnew[(size_t)j*HD + tid];

        {
            float v0 = s_s[w*128 + lane], v1 = s_s[w*128 + 64 + lane];
            float mt = wave_max(fmaxf(v0, v1));
            float mn = fmaxf(m_s[w], mt);
            float sc = __expf(m_s[w] - mn);
            float w0 = __expf(v0 - mn), w1 = __expf(v1 - mn);
            float lt = wave_sum(w0 + w1);
            s_s[w*128 + lane]      = w0;
            s_s[w*128 + 64 + lane] = w1;
            if(lane==0){ l_s[w] = l_s[w]*sc + lt; m_s[w] = mn; sc_s[w] = sc; }
        }
        __syncthreads();

        o0 *= sc_s[0]; o1 *= sc_s[1]; o2 *= sc_s[2]; o3 *= sc_s[3];
        int d = tid & 127, rh = tid >> 7;
        const float* vbase = V_s + rh*64*128 + d;
        const float* p0 = s_s + rh*64;
#pragma unroll 8
        for(int cc=0; cc<64; cc++){
            float v = vbase[cc*128];
            o0 += p0[cc]*v;
            o1 += p0[128+cc]*v;
            o2 += p0[256+cc]*v;
            o3 += p0[384+cc]*v;
        }
        __syncthreads();
    }

    int d = tid & 127, rh = tid >> 7;
    V_s[rh*512 + 0*128 + d] = o0;
    V_s[rh*512 + 1*128 + d] = o1;
    V_s[rh*512 + 2*128 + d] = o2;
    V_s[rh*512 + 3*128 + d] = o3;
    __syncthreads();
    if(tid < 128){
#pragma unroll
        for(int h=0;h<4;h++){
            float o = V_s[h*128 + tid] + V_s[512 + h*128 + tid];
            part_o[((size_t)(j*4+h)*nchunk + ci)*128 + tid] = o;
        }
    }
    if(tid < 4){
        part_m[(j*4+tid)*nchunk + ci] = m_s[tid];
        part_l[(j*4+tid)*nchunk + ci] = l_s[tid];
    }
}

// ---------- K4: combine chunks + gate. grid 16 x 128 ---------- (unchanged)
__global__ __launch_bounds__(128) void k_attn_red(const float* __restrict__ part_m,
                                                  const float* __restrict__ part_l,
                                                  const float* __restrict__ part_o,
                                                  const float* __restrict__ gate_sig,
                                                  float* __restrict__ attn,
                                                  int nchunk){
    __shared__ float e_s[64];
    __shared__ float lg_s;
    int h = blockIdx.x, tid = threadIdx.x, lane = tid&63, w = tid>>6;
    if(w == 0){
        float pm = (lane < nchunk) ? part_m[h*nchunk + lane] : -3.0e38f;
        float pl = (lane < nchunk) ? part_l[h*nchunk + lane] : 0.f;
        float mg = wave_max(pm);
        float e  = (lane < nchunk) ? __expf(pm - mg) : 0.f;
        float lg = wave_sum(pl * e);
        if(lane < 64) e_s[lane] = e;
        if(lane == 0) lg_s = lg;
    }
    __syncthreads();
    float lg = lg_s;
    float oa = 0.f;
    for(int i=0;i<nchunk;i++)
        oa += e_s[i]*part_o[((size_t)h*nchunk + i)*128 + tid];
    attn[h*128 + tid] = oa/lg * gate_sig[h*128 + tid];
}

// ---------- K5: Wo matvec + residual, counted-vmcnt streamed. grid 256 x 512 ---------- (unchanged)
__global__ __launch_bounds__(512) void k_wo(const float* __restrict__ Wo,
                                            const float* __restrict__ attn,
                                            const float* __restrict__ resid,
                                            float* __restrict__ x){
    __shared__ __align__(16) float wlds[8*2048];   // 64KB: one row per wave
    int tid = threadIdx.x, wid = tid>>6, lane = tid&63;
    int row = blockIdx.x*8 + wid;
    const float* wr = Wo + (size_t)row*H;
    float4 av[8];
#pragma unroll
    for(int i=0;i<8;i++) av[i] = *(const float4*)(attn + i*256 + lane*4);
#pragma unroll
    for(int i=0;i<8;i++) stage16(wr + i*256 + lane*4, wlds + wid*2048 + i*256);
    const float* wb = wlds + wid*2048 + lane*4;
    float acc = 0.f;
#define WSTEP(I,N) { WV(N); float4 rv = *(const float4*)(wb + I*256); \
                     acc += rv.x*av[I].x + rv.y*av[I].y + rv.z*av[I].z + rv.w*av[I].w; }
    WSTEP(0,7) WSTEP(1,6) WSTEP(2,5) WSTEP(3,4)
    WSTEP(4,3) WSTEP(5,2) WSTEP(6,1) WSTEP(7,0)
#undef WSTEP
    acc = wave_sum(acc);
    if(lane==0) x[row] = resid[row] + acc;
}

// ---------- K6a: ln2-RMSNorm + GATE matvec + SiLU. grid 2048 x 256 ----------
// Split of k_gateup (diagnostic: frees top-5 slots so hidden kernels surface).
// Bit-exact: same norm arithmetic, same per-row FMA order; silu(ag) -> gtmp.
// 40KB LDS -> 3 blocks/CU.
__global__ __launch_bounds__(256,3) void k_gate(const float* __restrict__ Wg,
                                                const float* __restrict__ xres,
                                                const float* __restrict__ ln2,
                                                float* __restrict__ gtmp){
    __shared__ __align__(16) float hw[H];          // 8KB
    __shared__ __align__(16) float wlds[4*2048];   // 32KB: one row per wave
    __shared__ float red[4];
    int tid = threadIdx.x, wid = tid>>6, lane = tid&63;
    int row = blockIdx.x*4 + wid;
    const float* gr = Wg + (size_t)row*H;
    float4 a = *(const float4*)(xres + (size_t)tid*8);
    float4 b = *(const float4*)(xres + (size_t)tid*8 + 4);
    float4 wa = *(const float4*)(ln2 + (size_t)tid*8);
    float4 wb = *(const float4*)(ln2 + (size_t)tid*8 + 4);
#pragma unroll
    for(int i=0;i<8;i++) stage16(gr + i*256 + lane*4, wlds + wid*2048 + i*256);

    float x[8] = {a.x,a.y,a.z,a.w,b.x,b.y,b.z,b.w};
    float ss = 0.f;
#pragma unroll
    for(int i=0;i<8;i++) ss += x[i]*x[i];
    ss = wave_sum(ss);
    if(lane==0) red[wid] = ss;
    __syncthreads();
    float tot = red[0]+red[1]+red[2]+red[3];
    float rs = rsqrtf(tot/(float)H + EPS);
    *(float4*)(hw + tid*8)     = make_float4(x[0]*rs*wa.x, x[1]*rs*wa.y, x[2]*rs*wa.z, x[3]*rs*wa.w);
    *(float4*)(hw + tid*8 + 4) = make_float4(x[4]*rs*wb.x, x[5]*rs*wb.y, x[6]*rs*wb.z, x[7]*rs*wb.w);
    __syncthreads();

    float ag = 0.f;
#pragma unroll
    for(int i=0;i<8;i++){
        float4 gv = *(const float4*)(wlds + wid*2048 + i*256 + lane*4);
        float4 hv = *(const float4*)(hw + i*256 + lane*4);
        ag += gv.x*hv.x + gv.y*hv.y + gv.z*hv.z + gv.w*hv.w;
    }
    ag = wave_sum(ag);
    if(lane==0) gtmp[row] = ag/(1.f + __expf(-ag));
}

// ---------- K6b: ln2-RMSNorm + UP matvec, * silu(gate). grid 2048 x 256 ----------
__global__ __launch_bounds__(256,3) void k_up(const float* __restrict__ Wu,
                                              const float* __restrict__ xres,
                                              const float* __restrict__ ln2,
                                              const float* __restrict__ gtmp,
                                              float* __restrict__ act){
    __shared__ __align__(16) float hw[H];
    __shared__ __align__(16) float wlds[4*2048];
    __shared__ float red[4];
    int tid = threadIdx.x, wid = tid>>6, lane = tid&63;
    int row = blockIdx.x*4 + wid;
    const float* ur = Wu + (size_t)row*H;
    float4 a = *(const float4*)(xres + (size_t)tid*8);
    float4 b = *(const float4*)(xres + (size_t)tid*8 + 4);
    float4 wa = *(const float4*)(ln2 + (size_t)tid*8);
    float4 wb = *(const float4*)(ln2 + (size_t)tid*8 + 4);
#pragma unroll
    for(int i=0;i<8;i++) stage16(ur + i*256 + lane*4, wlds + wid*2048 + i*256);

    float x[8] = {a.x,a.y,a.z,a.w,b.x,b.y,b.z,b.w};
    float ss = 0.f;
#pragma unroll
    for(int i=0;i<8;i++) ss += x[i]*x[i];
    ss = wave_sum(ss);
    if(lane==0) red[wid] = ss;
    __syncthreads();
    float tot = red[0]+red[1]+red[2]+red[3];
    float rs = rsqrtf(tot/(float)H + EPS);
    *(float4*)(hw + tid*8)     = make_float4(x[0]*rs*wa.x, x[1]*rs*wa.y, x[2]*rs*wa.z, x[3]*rs*wa.w);
    *(float4*)(hw + tid*8 + 4) = make_float4(x[4]*rs*wb.x, x[5]*rs*wb.y, x[6]*rs*wb.z, x[7]*rs*wb.w);
    __syncthreads();

    float au = 0.f;
#pragma unroll
    for(int i=0;i<8;i++){
        float4 uv = *(const float4*)(wlds + wid*2048 + i*256 + lane*4);
        float4 hv = *(const float4*)(hw + i*256 + lane*4);
        au += uv.x*hv.x + uv.y*hv.y + uv.z*hv.z + uv.w*hv.w;
    }
    au = wave_sum(au);
    if(lane==0) act[row] = gtmp[row]*au;
}

// ---------- K7: down matvec + residual, counted-vmcnt streamed. grid 1024 x 256 ---------- (unchanged)
__global__ __launch_bounds__(256,2) void k_down(const float* __restrict__ Wd,
                                                const float* __restrict__ act,
                                                const float* __restrict__ x,
                                                float* __restrict__ out){
    __shared__ __align__(16) float wlds[4*4096];   // 64KB: 16KB half-row per wave
    __shared__ float part[4];
    int tid = threadIdx.x, wid = tid>>6, lane = tid&63;
    int row  = blockIdx.x*2 + (wid>>1);
    int half = wid&1;
    const float* wr = Wd + (size_t)row*IDIM + half*4096;
    const float* ab = act + half*4096;
    float4 av[16];
#pragma unroll
    for(int i=0;i<16;i++) av[i] = *(const float4*)(ab + i*256 + lane*4);
#pragma unroll
    for(int i=0;i<16;i++) stage16(wr + i*256 + lane*4, wlds + wid*4096 + i*256);
    const float* wb = wlds + wid*4096 + lane*4;
    float acc = 0.f;
#define DSTEP(I,N) { WV(N); float4 rv = *(const float4*)(wb + I*256); \
                     acc += rv.x*av[I].x + rv.y*av[I].y + rv.z*av[I].z + rv.w*av[I].w; }
    DSTEP(0,15)  DSTEP(1,14)  DSTEP(2,13)  DSTEP(3,12)
    DSTEP(4,11)  DSTEP(5,10)  DSTEP(6,9)   DSTEP(7,8)
    DSTEP(8,7)   DSTEP(9,6)   DSTEP(10,5)  DSTEP(11,4)
    DSTEP(12,3)  DSTEP(13,2)  DSTEP(14,1)  DSTEP(15,0)
#undef DSTEP
    acc = wave_sum(acc);
    if(lane==0) part[wid] = acc;
    __syncthreads();
    if(tid < 2){
        int rr = blockIdx.x*2 + tid;
        out[rr] = x[rr] + part[tid*2] + part[tid*2+1];
    }
}

extern "C" void kernel_launch(void* const* d_in, const int* in_sizes, int n_in,
                              void* d_out, int out_size, void* d_ws, size_t ws_size,
                              hipStream_t stream){
    const float* hs   = (const float*)d_in[0];
    const int*   pos  = (const int*)d_in[1];
    const float* mask = (const float*)d_in[2];
    const float* Wq   = (const float*)d_in[3];
    const float* Wk   = (const float*)d_in[4];
    const float* Wv   = (const float*)d_in[5];
    const float* Wo   = (const float*)d_in[6];
    const float* qn   = (const float*)d_in[7];
    const float* kn   = (const float*)d_in[8];
    const float* ln1  = (const float*)d_in[9];
    const float* ln2  = (const float*)d_in[10];
    const float* Wg   = (const float*)d_in[11];
    const float* Wu   = (const float*)d_in[12];
    const float* Wd   = (const float*)d_in[13];
    const float* cache= (const float*)d_in[14];
    const float* rc   = (const float*)d_in[15];
    const float* rsn  = (const float*)d_in[16];
    float* out = (float*)d_out;

    float* ws       = (float*)d_ws;
    float* qg       = ws;                // 4096
    float* kvec     = ws + 4096;         // 512
    float* vvec     = ws + 4608;         // 512
    float* q_rope   = ws + 5120;         // 2048
    float* gate_sig = ws + 7168;         // 2048
    float* xres     = ws + 9216;         // 2048
    float* gtmp     = ws + 13312;        // 2048 (8192 needed? no: IDIM outputs -> 8192) 
    float* attn     = ws + 15360;        // 2048
    float* act      = ws + 17408;        // 8192
    float* knew     = ws + 25600;        // 512
    float* vnew     = ws + 26112;        // 512
    // gtmp needs IDIM=8192 floats; 13312..15360 is only 2048. Move gtmp after part arrays.
    int nchunk = 64;
    while(nchunk > 1){
        size_t need = (size_t)(26624 + 2*NH*nchunk + (size_t)NH*nchunk*128 + IDIM) * 4;
        if(need <= ws_size) break;
        nchunk >>= 1;
    }
    int chunk = CTX / nchunk;
    float* part_m = ws + 26624;
    float* part_l = part_m + NH*nchunk;
    float* part_o = part_l + NH*nchunk;
    gtmp = part_o + (size_t)NH*nchunk*128;   // 8192 floats

    k_qkv<<<576,512,0,stream>>>(Wq, Wk, Wv, hs, ln1, qg, kvec, vvec);
    k_rope<<<20,64,0,stream>>>(qg, kvec, vvec, pos, qn, kn, rc, rsn, q_rope, gate_sig, knew, vnew);
    dim3 g3(nchunk, NKV);
    k_attn_part<<<g3,256,0,stream>>>(cache, q_rope, mask, pos, knew, vnew,
                                     part_m, part_l, part_o, nchunk, chunk);
    k_attn_red<<<16,128,0,stream>>>(part_m, part_l, part_o, gate_sig, attn, nchunk);
    k_wo<<<256,512,0,stream>>>(Wo, attn, hs, xres);
    k_gate<<<2048,256,0,stream>>>(Wg, xres, ln2, gtmp);
    k_up<<<2048,256,0,stream>>>(Wu, xres, ln2, gtmp, act);
    k_down<<<1024,256,0,stream>>>(Wd, act, xres, out);
}